// Round 1
// baseline (23591.586 us; speedup 1.0000x reference)
//
#include <hip/hip_runtime.h>
#include <cstddef>
#include <cstdint>

// Pointer-network decoder, B=64, T=128, D=512, H=512.
// Strategy: precompute all step-invariant GEMMs (xW table, ctx_lin, ctxWo),
// then one persistent 256-block kernel runs the 128-step recurrence with a
// custom device-scope grid barrier (4 barriers/step).

#define NEGV (-1e9f)

static constexpr int B = 64, T = 128, D = 512, H = 512;
static constexpr int NB = 256;          // persistent grid size
static constexpr int NTHR = 256;

// ---- workspace layout (element offsets, fp32) ----
static constexpr size_t OFF_BAR  = 0;                         // 64 floats reserved (barrier)
static constexpr size_t OFF_H    = 64;                        // [64][512] h state
static constexpr size_t OFF_C    = OFF_H    + 64*512;         // [64][512] c state
static constexpr size_t OFF_HL   = OFF_C    + 64*512;         // [64][512] h_lstm
static constexpr size_t OFF_INP  = OFF_HL   + 64*512;         // [64][512] inp (incl b_inp)
static constexpr size_t OFF_HW   = OFF_INP  + 64*512;         // [64][512] h_lstm@Wout2^T + b_out
static constexpr size_t OFF_E    = OFF_HW   + 64*512;         // [64][128] masked scores
static constexpr size_t OFF_MASK = OFF_E    + 64*128;         // [64][128]
static constexpr size_t OFF_ML   = OFF_MASK + 64*128;         // [64] max_len
static constexpr size_t OFF_SEL  = OFF_ML   + 64;             // [64] (int)
static constexpr size_t OFF_X0W  = OFF_SEL  + 64;             // [2048] input0@W_ih^T + biases
static constexpr size_t OFF_XW   = OFF_X0W  + 2048;           // [8192][2048]
static constexpr size_t OFF_CTX  = OFF_XW   + (size_t)8192*2048; // [8192][512] ctx_lin
static constexpr size_t OFF_CWO  = OFF_CTX  + (size_t)8192*512;  // [8192][512] ctx_lin@Wout1^T
static constexpr size_t WS_FLOATS= OFF_CWO  + (size_t)8192*512;  // ~101.4 MB

__device__ __forceinline__ float sigf(float x) { return 1.0f / (1.0f + expf(-x)); }

// ---------------- grid barrier ----------------
struct GBar { unsigned cnt; unsigned gen; };

__device__ __forceinline__ void gridbar(GBar* gb) {
  __syncthreads();                       // compiler emits vmcnt(0) drain before s_barrier
  if (threadIdx.x == 0) {
    unsigned g = __hip_atomic_load(&gb->gen, __ATOMIC_ACQUIRE, __HIP_MEMORY_SCOPE_AGENT);
    unsigned p = __hip_atomic_fetch_add(&gb->cnt, 1u, __ATOMIC_ACQ_REL, __HIP_MEMORY_SCOPE_AGENT);
    if (p == (unsigned)NB - 1u) {
      __hip_atomic_store(&gb->cnt, 0u, __ATOMIC_RELAXED, __HIP_MEMORY_SCOPE_AGENT);
      __hip_atomic_fetch_add(&gb->gen, 1u, __ATOMIC_ACQ_REL, __HIP_MEMORY_SCOPE_AGENT);
    } else {
      unsigned spins = 0;
      while (__hip_atomic_load(&gb->gen, __ATOMIC_ACQUIRE, __HIP_MEMORY_SCOPE_AGENT) == g) {
        __builtin_amdgcn_s_sleep(2);
        if (++spins > 50000000u) break;  // liveness escape hatch (normally never hit)
      }
    }
  }
  __syncthreads();
}

// ---------------- precompute: x0 row ----------------
// x0w[j] = input0 . W_ih[j,:] + b_ih[j] + b_hh[j]; one wave per j.
__global__ __launch_bounds__(256) void x0w_kernel(
    const float* __restrict__ input0, const float* __restrict__ W_ih,
    const float* __restrict__ b_ih, const float* __restrict__ b_hh,
    float* __restrict__ x0w) {
  int wid = (blockIdx.x * 256 + threadIdx.x) >> 6;   // 0..2047
  int l = threadIdx.x & 63;
  const float* wr = W_ih + (size_t)wid * 512;
  float acc = 0.f;
  #pragma unroll
  for (int q = 0; q < 8; ++q) acc += input0[l*8+q] * wr[l*8+q];
  #pragma unroll
  for (int off = 32; off; off >>= 1) acc += __shfl_xor(acc, off, 64);
  if (l == 0) x0w[wid] = acc + b_ih[wid] + b_hh[wid];
}

// ---------------- precompute: tiled fp32 GEMM, C = A@B^T + bias1 + bias2 ----------------
// A:[M,K] row-major, B rows at stride ldb (uses first K cols). 128x128 tile, 8x8 micro.
__global__ __launch_bounds__(256) void gemm_abt(
    const float* __restrict__ A, const float* __restrict__ Bm,
    const float* __restrict__ bias1, const float* __restrict__ bias2,
    float* __restrict__ C, int M, int N, int K, int ldb) {
  __shared__ float As[16][132];
  __shared__ float Bs[16][132];
  const int t = threadIdx.x;
  const int tx = t & 15, ty = t >> 4;
  const int mbase = blockIdx.y * 128, nbase = blockIdx.x * 128;
  float acc[8][8] = {};
  for (int kc = 0; kc < K; kc += 16) {
    __syncthreads();
    #pragma unroll
    for (int r = 0; r < 2; ++r) {
      int q = r * 256 + t;              // float4 index, 512 per tile
      int row = q >> 2, kq = (q & 3) * 4;
      float4 va = *(const float4*)&A[(size_t)(mbase + row) * K + kc + kq];
      As[kq+0][row] = va.x; As[kq+1][row] = va.y; As[kq+2][row] = va.z; As[kq+3][row] = va.w;
      float4 vb = *(const float4*)&Bm[(size_t)(nbase + row) * ldb + kc + kq];
      Bs[kq+0][row] = vb.x; Bs[kq+1][row] = vb.y; Bs[kq+2][row] = vb.z; Bs[kq+3][row] = vb.w;
    }
    __syncthreads();
    #pragma unroll
    for (int kk = 0; kk < 16; ++kk) {
      float a[8], b[8];
      *(float4*)(a)   = *(const float4*)&As[kk][ty*8];
      *(float4*)(a+4) = *(const float4*)&As[kk][ty*8+4];
      *(float4*)(b)   = *(const float4*)&Bs[kk][tx*8];
      *(float4*)(b+4) = *(const float4*)&Bs[kk][tx*8+4];
      #pragma unroll
      for (int i = 0; i < 8; ++i)
        #pragma unroll
        for (int j = 0; j < 8; ++j)
          acc[i][j] = fmaf(a[i], b[j], acc[i][j]);
    }
  }
  float bv[8];
  #pragma unroll
  for (int q = 0; q < 8; ++q) {
    int n = nbase + tx*8 + q;
    bv[q] = (bias1 ? bias1[n] : 0.f) + (bias2 ? bias2[n] : 0.f);
  }
  #pragma unroll
  for (int i = 0; i < 8; ++i) {
    size_t m = (size_t)(mbase + ty*8 + i);
    float4 o0 = make_float4(acc[i][0]+bv[0], acc[i][1]+bv[1], acc[i][2]+bv[2], acc[i][3]+bv[3]);
    float4 o1 = make_float4(acc[i][4]+bv[4], acc[i][5]+bv[5], acc[i][6]+bv[6], acc[i][7]+bv[7]);
    *(float4*)&C[m * N + nbase + tx*8]     = o0;
    *(float4*)&C[m * N + nbase + tx*8 + 4] = o1;
  }
}

// ---------------- the persistent decoder ----------------
union SMem {
  float hbuf[64][260];   // staged h / h_lstm, padded stride 260 (16B-aligned, conflict-free)
  float alpha[128];      // phase D softmax
};

__global__ __launch_bounds__(256) void decoder_kernel(
    const float* __restrict__ h0, const float* __restrict__ c0,
    const float* __restrict__ cmask,
    const float* __restrict__ W_hh,
    const float* __restrict__ W_inp, const float* __restrict__ b_inp_,
    const float* __restrict__ W_out, const float* __restrict__ b_out_,
    const float* __restrict__ vvec,
    float* __restrict__ ws, float* __restrict__ out) {
  __shared__ SMem sm;
  GBar* gb = (GBar*)ws;
  float* hglob = ws + OFF_H;
  float* cst   = ws + OFF_C;
  float* hlp   = ws + OFF_HL;
  float* inpp  = ws + OFF_INP;
  float* hwp   = ws + OFF_HW;
  float* ep    = ws + OFF_E;
  float* maskp = ws + OFF_MASK;
  float* mlp   = ws + OFF_ML;
  int*   selp  = (int*)(ws + OFF_SEL);
  const float* x0wp = ws + OFF_X0W;
  const float* xwp  = ws + OFF_XW;
  const float* ctxp = ws + OFF_CTX;
  const float* cwop = ws + OFF_CWO;

  float* out_scores = out;
  float* out_ptrs   = out + (size_t)B*T*T;
  float* out_hf     = out_ptrs + (size_t)B*T;
  float* out_cf     = out_hf + (size_t)B*H;

  const int g = blockIdx.x, t = threadIdx.x;
  const int w = t >> 6, l = t & 63;

  auto stage = [&](const float* src, int ch) {
    #pragma unroll
    for (int r = 0; r < 16; ++r) {
      int q = r * 256 + t;               // float4 index; wave writes one row
      int bb = q >> 6, jj = q & 63;
      float4 v4 = *(const float4*)&src[(size_t)bb * 512 + ch * 256 + jj * 4];
      *(float4*)&sm.hbuf[bb][jj * 4] = v4;
    }
  };

  // ---- init: copy states, mask, max_len ----
  {
    const size_t gid = (size_t)g * NTHR + t;   // 0..65535
    if (gid < 32768) hglob[gid] = h0[gid];
    else             cst[gid - 32768] = c0[gid - 32768];
    if (gid < 8192)  maskp[gid] = cmask[gid];
    if (gid < 64) {
      float s_ = 0.f;
      for (int q = 0; q < 128; ++q) s_ += cmask[gid * 128 + q];
      mlp[gid] = s_;
    }
  }
  gridbar(gb);

  // phase-C per-lane constants (v slice) hoisted
  float vreg[8];
  *(float4*)(vreg)   = *(const float4*)&vvec[l*8];
  *(float4*)(vreg+4) = *(const float4*)&vvec[l*8+4];

  for (int s = 0; s < T; ++s) {
    // ================= PHASE A: gates -> c_t, h_lstm =================
    // waves 0-1 of every block: k = g*2 + w, all 4 gates per wave, lane = batch.
    {
      const int k = g * 2 + w;           // valid when w < 2
      const float* r0 = W_hh + (size_t)k * 512;
      const float* r1 = r0 + (size_t)512  * 512;
      const float* r2 = r0 + (size_t)1024 * 512;
      const float* r3 = r0 + (size_t)1536 * 512;
      float ai = 0.f, af = 0.f, ag = 0.f, ao = 0.f;
      for (int ch = 0; ch < 2; ++ch) {
        __syncthreads();
        stage(hglob, ch);
        __syncthreads();
        if (w < 2) {
          const float* p0 = r0 + ch * 256;
          const float* p1 = r1 + ch * 256;
          const float* p2 = r2 + ch * 256;
          const float* p3 = r3 + ch * 256;
          for (int j = 0; j < 256; j += 4) {
            float4 hv = *(const float4*)&sm.hbuf[l][j];
            float4 w0 = *(const float4*)&p0[j];
            float4 w1 = *(const float4*)&p1[j];
            float4 w2 = *(const float4*)&p2[j];
            float4 w3 = *(const float4*)&p3[j];
            ai = fmaf(hv.x,w0.x, fmaf(hv.y,w0.y, fmaf(hv.z,w0.z, fmaf(hv.w,w0.w, ai))));
            af = fmaf(hv.x,w1.x, fmaf(hv.y,w1.y, fmaf(hv.z,w1.z, fmaf(hv.w,w1.w, af))));
            ag = fmaf(hv.x,w2.x, fmaf(hv.y,w2.y, fmaf(hv.z,w2.z, fmaf(hv.w,w2.w, ag))));
            ao = fmaf(hv.x,w3.x, fmaf(hv.y,w3.y, fmaf(hv.z,w3.z, fmaf(hv.w,w3.w, ao))));
          }
        }
      }
      if (w < 2) {
        const float* xrow = (s == 0) ? x0wp
                          : (xwp + ((size_t)l * 128 + (size_t)selp[l]) * 2048);
        float gi = ai + xrow[k];
        float gf = af + xrow[k + 512];
        float gg = ag + xrow[k + 1024];
        float go = ao + xrow[k + 1536];
        size_t idx = (size_t)l * 512 + k;
        float ct = sigf(gf) * cst[idx] + sigf(gi) * tanhf(gg);
        cst[idx] = ct;
        hlp[idx] = sigf(go) * tanhf(ct);
      }
    }
    gridbar(gb);

    // ================= PHASE B: inp = hl@W_inp^T + b_inp ; hWo2 = hl@Wout2^T + b_out ====
    {
      const int i = g * 2 + w;           // valid when w < 2
      const float* wi = W_inp + (size_t)i * 512;
      const float* wo = W_out + (size_t)i * 1024 + 512;
      float a1 = 0.f, a2 = 0.f;
      for (int ch = 0; ch < 2; ++ch) {
        __syncthreads();
        stage(hlp, ch);
        __syncthreads();
        if (w < 2) {
          const float* pi_ = wi + ch * 256;
          const float* po_ = wo + ch * 256;
          for (int j = 0; j < 256; j += 4) {
            float4 hv = *(const float4*)&sm.hbuf[l][j];
            float4 w0 = *(const float4*)&pi_[j];
            float4 w1 = *(const float4*)&po_[j];
            a1 = fmaf(hv.x,w0.x, fmaf(hv.y,w0.y, fmaf(hv.z,w0.z, fmaf(hv.w,w0.w, a1))));
            a2 = fmaf(hv.x,w1.x, fmaf(hv.y,w1.y, fmaf(hv.z,w1.z, fmaf(hv.w,w1.w, a2))));
          }
        }
      }
      if (w < 2) {
        size_t idx = (size_t)l * 512 + i;
        inpp[idx] = a1 + b_inp_[i];
        hwp[idx]  = a2 + b_out_[i];
      }
    }
    gridbar(gb);

    // ================= PHASE C: e[b,t] = v . tanh(ctx_lin + inp), write masked scores ====
    {
      const int b_ = g >> 2;
      const int tbase = (g & 3) * 32 + w * 8;
      float ii[8];
      *(float4*)(ii)   = *(const float4*)&inpp[(size_t)b_ * 512 + l*8];
      *(float4*)(ii+4) = *(const float4*)&inpp[(size_t)b_ * 512 + l*8 + 4];
      for (int q = 0; q < 8; ++q) {
        int tc = tbase + q;
        const float* cr = ctxp + ((size_t)(b_ * 128 + tc)) * 512 + l * 8;
        float4 c0_ = *(const float4*)cr;
        float4 c1_ = *(const float4*)(cr + 4);
        float acc = vreg[0]*tanhf(c0_.x + ii[0]) + vreg[1]*tanhf(c0_.y + ii[1])
                  + vreg[2]*tanhf(c0_.z + ii[2]) + vreg[3]*tanhf(c0_.w + ii[3])
                  + vreg[4]*tanhf(c1_.x + ii[4]) + vreg[5]*tanhf(c1_.y + ii[5])
                  + vreg[6]*tanhf(c1_.z + ii[6]) + vreg[7]*tanhf(c1_.w + ii[7]);
        #pragma unroll
        for (int off = 32; off; off >>= 1) acc += __shfl_xor(acc, off, 64);
        if (l == 0) {
          float mk = maskp[b_ * 128 + tc];
          float sc = (mk > 0.f) ? acc : NEGV;
          ep[b_ * 128 + tc] = sc;                                     // masked score
          out_scores[((size_t)b_ * 128 + s) * 128 + tc] = sc;         // outputs[b,s,t]
        }
      }
    }
    gridbar(gb);

    // ================= PHASE D: softmax, selection, h_t ==============================
    {
      const int b_ = g >> 2, is = (g & 3) << 7;
      if (w == 0) {
        float s0 = ep[b_ * 128 + l], s1 = ep[b_ * 128 + 64 + l];
        float mx = fmaxf(s0, s1);
        #pragma unroll
        for (int off = 32; off; off >>= 1) mx = fmaxf(mx, __shfl_xor(mx, off, 64));
        float x0 = expf(s0 - mx), x1 = expf(s1 - mx);
        float sum = x0 + x1;
        #pragma unroll
        for (int off = 32; off; off >>= 1) sum += __shfl_xor(sum, off, 64);
        float a0 = x0 / sum, a1 = x1 / sum;
        sm.alpha[l] = a0; sm.alpha[64 + l] = a1;
        if ((g & 3) == 0) {                 // one block per batch does selection
          float m0 = maskp[b_ * 128 + l], m1 = maskp[b_ * 128 + 64 + l];
          float p0 = a0 * m0, p1 = a1 * m1;
          float pv; int pi;
          if (p1 > p0) { pv = p1; pi = l + 64; } else { pv = p0; pi = l; }
          #pragma unroll
          for (int off = 32; off; off >>= 1) {
            float ov = __shfl_xor(pv, off, 64);
            int   oi = __shfl_xor(pi, off, 64);
            if (ov > pv || (ov == pv && oi < pi)) { pv = ov; pi = oi; }
          }
          if (l == 0) {
            int se = (mlp[b_] > (float)s) ? pi : s;
            selp[b_] = se;
            maskp[b_ * 128 + se] = 0.f;
            out_ptrs[b_ * 128 + s] = (float)se;
          }
        }
      }
      __syncthreads();
      if (t < 128) {
        int i = is + t;
        float acc = hwp[(size_t)b_ * 512 + i];      // includes b_out
        const float* cw = cwop + (size_t)b_ * 128 * 512 + i;
        for (int tc = 0; tc < 128; ++tc)
          acc = fmaf(sm.alpha[tc], cw[(size_t)tc * 512], acc);
        hglob[(size_t)b_ * 512 + i] = tanhf(acc);
      }
    }
    gridbar(gb);
  }

  // ---- epilogue: h_f, c_f ----
  {
    const size_t gid = (size_t)g * NTHR + t;
    if (gid < 32768) out_hf[gid] = hglob[gid];
    else             out_cf[gid - 32768] = cst[gid - 32768];
  }
}

extern "C" void kernel_launch(void* const* d_in, const int* in_sizes, int n_in,
                              void* d_out, int out_size, void* d_ws, size_t ws_size,
                              hipStream_t stream) {
  (void)in_sizes; (void)n_in; (void)out_size; (void)ws_size;
  const float* inputs    = (const float*)d_in[0];
  const float* h0        = (const float*)d_in[1];
  const float* c0        = (const float*)d_in[2];
  const float* candidate = (const float*)d_in[3];
  const float* cmask     = (const float*)d_in[4];
  const float* input0    = (const float*)d_in[5];
  const float* W_ih      = (const float*)d_in[6];
  const float* b_ih      = (const float*)d_in[7];
  const float* W_hh      = (const float*)d_in[8];
  const float* b_hh      = (const float*)d_in[9];
  const float* W_out     = (const float*)d_in[10];
  const float* b_out     = (const float*)d_in[11];
  const float* W_inp     = (const float*)d_in[12];
  const float* b_inp     = (const float*)d_in[13];
  const float* W_ctx     = (const float*)d_in[14];
  const float* b_ctx     = (const float*)d_in[15];
  const float* v         = (const float*)d_in[16];
  float* ws  = (float*)d_ws;
  float* outp = (float*)d_out;

  // zero the barrier
  hipMemsetAsync(d_ws, 0, 256, stream);

  // x0 row: input0 @ W_ih^T + b_ih + b_hh
  x0w_kernel<<<512, 256, 0, stream>>>(input0, W_ih, b_ih, b_hh, ws + OFF_X0W);

  // xW table: inputs(8192,512) @ W_ih(2048,512)^T + b_ih + b_hh
  gemm_abt<<<dim3(16, 64), 256, 0, stream>>>(inputs, W_ih, b_ih, b_hh,
                                             ws + OFF_XW, 8192, 2048, 512, 512);
  // ctx_lin: candidate(8192,512) @ W_ctx(512,512)^T + b_ctx
  gemm_abt<<<dim3(4, 64), 256, 0, stream>>>(candidate, W_ctx, b_ctx, nullptr,
                                            ws + OFF_CTX, 8192, 512, 512, 512);
  // ctxWo: ctx_lin @ W_out[:, :512]^T   (W_out row stride 1024)
  gemm_abt<<<dim3(4, 64), 256, 0, stream>>>(ws + OFF_CTX, W_out, nullptr, nullptr,
                                            ws + OFF_CWO, 8192, 512, 512, 1024);

  decoder_kernel<<<NB, NTHR, 0, stream>>>(h0, c0, cmask, W_hh, W_inp, b_inp,
                                          W_out, b_out, v, ws, outp);
}

// Round 3
// 13335.312 us; speedup vs baseline: 1.7691x; 1.7691x over previous
//
#include <hip/hip_runtime.h>
#include <cstddef>
#include <cstdint>

// Pointer-network decoder, B=64, T=128, D=512, H=512.
// Precompute step-invariant GEMMs (xW table, ctx_lin, ctxWo), then one
// persistent 256-block kernel runs the 128-step recurrence with a
// flag-array device-scope grid barrier (4 barriers/step).

#define NEGV (-1e9f)

static constexpr int B = 64, T = 128, D = 512, H = 512;
static constexpr int NB = 256;          // persistent grid size
static constexpr int NTHR = 256;

// ---- workspace layout (element offsets, fp32) ----
static constexpr size_t OFF_FLAGS = 0;                        // 256 ints (barrier flags)
static constexpr size_t OFF_H    = 512;                       // [64][512] h state
static constexpr size_t OFF_C    = OFF_H    + 64*512;         // [512][64] c state (TRANSPOSED)
static constexpr size_t OFF_HL   = OFF_C    + 64*512;         // [64][512] h_lstm
static constexpr size_t OFF_INP  = OFF_HL   + 64*512;         // [64][512] inp (incl b_inp)
static constexpr size_t OFF_HW   = OFF_INP  + 64*512;         // [64][512] h_lstm@Wout2^T + b_out
static constexpr size_t OFF_E    = OFF_HW   + 64*512;         // [64][128] masked scores
static constexpr size_t OFF_MASK = OFF_E    + 64*128;         // [64][128]
static constexpr size_t OFF_ML   = OFF_MASK + 64*128;         // [64] max_len
static constexpr size_t OFF_SEL  = OFF_ML   + 64;             // [64] (int)
static constexpr size_t OFF_X0W  = OFF_SEL  + 64;             // [2048] input0@W_ih^T + biases
static constexpr size_t OFF_XW   = OFF_X0W  + 2048;           // [8192][2048]
static constexpr size_t OFF_CTX  = OFF_XW   + (size_t)8192*2048; // [8192][512] ctx_lin
static constexpr size_t OFF_CWO  = OFF_CTX  + (size_t)8192*512;  // [8192][512] ctx_lin@Wout1^T

__device__ __forceinline__ float sigf(float x) { return 1.0f / (1.0f + expf(-x)); }

// ---------------- grid barrier: per-block flags, monotonic targets ----------------
__device__ __forceinline__ void gridbar(int* flags, int target, int g, int t) {
  __syncthreads();   // all waves of this block done with the phase
  if (t == 0) {
    __hip_atomic_store(&flags[g], target, __ATOMIC_RELEASE, __HIP_MEMORY_SCOPE_AGENT);
  }
  if (t < 64) {
    const int i0 = t << 2;
    int miss = 0;
    for (;;) {
      int f0 = __hip_atomic_load(&flags[i0+0], __ATOMIC_RELAXED, __HIP_MEMORY_SCOPE_AGENT);
      int f1 = __hip_atomic_load(&flags[i0+1], __ATOMIC_RELAXED, __HIP_MEMORY_SCOPE_AGENT);
      int f2 = __hip_atomic_load(&flags[i0+2], __ATOMIC_RELAXED, __HIP_MEMORY_SCOPE_AGENT);
      int f3 = __hip_atomic_load(&flags[i0+3], __ATOMIC_RELAXED, __HIP_MEMORY_SCOPE_AGENT);
      bool ok = (f0 >= target) && (f1 >= target) && (f2 >= target) && (f3 >= target);
      if (__all(ok)) break;
      if (++miss > 5000000) break;   // liveness escape hatch (never hit in practice)
    }
  }
  __syncthreads();
  __builtin_amdgcn_fence(__ATOMIC_ACQUIRE, "agent");   // pairs with each block's release store
}

// ---------------- precompute: x0 row ----------------
__global__ __launch_bounds__(256) void x0w_kernel(
    const float* __restrict__ input0, const float* __restrict__ W_ih,
    const float* __restrict__ b_ih, const float* __restrict__ b_hh,
    float* __restrict__ x0w) {
  int wid = (blockIdx.x * 256 + threadIdx.x) >> 6;   // 0..2047
  int l = threadIdx.x & 63;
  const float* wr = W_ih + (size_t)wid * 512;
  float acc = 0.f;
  #pragma unroll
  for (int q = 0; q < 8; ++q) acc += input0[l*8+q] * wr[l*8+q];
  #pragma unroll
  for (int off = 32; off; off >>= 1) acc += __shfl_xor(acc, off, 64);
  if (l == 0) x0w[wid] = acc + b_ih[wid] + b_hh[wid];
}

// ---------------- precompute: tiled fp32 GEMM, C = A@B^T + bias1 + bias2 ----------------
__global__ __launch_bounds__(256) void gemm_abt(
    const float* __restrict__ A, const float* __restrict__ Bm,
    const float* __restrict__ bias1, const float* __restrict__ bias2,
    float* __restrict__ C, int M, int N, int K, int ldb) {
  __shared__ float As[16][132];
  __shared__ float Bs[16][132];
  const int t = threadIdx.x;
  const int tx = t & 15, ty = t >> 4;
  const int mbase = blockIdx.y * 128, nbase = blockIdx.x * 128;
  float acc[8][8] = {};
  for (int kc = 0; kc < K; kc += 16) {
    __syncthreads();
    #pragma unroll
    for (int r = 0; r < 2; ++r) {
      int q = r * 256 + t;
      int row = q >> 2, kq = (q & 3) * 4;
      float4 va = *(const float4*)&A[(size_t)(mbase + row) * K + kc + kq];
      As[kq+0][row] = va.x; As[kq+1][row] = va.y; As[kq+2][row] = va.z; As[kq+3][row] = va.w;
      float4 vb = *(const float4*)&Bm[(size_t)(nbase + row) * ldb + kc + kq];
      Bs[kq+0][row] = vb.x; Bs[kq+1][row] = vb.y; Bs[kq+2][row] = vb.z; Bs[kq+3][row] = vb.w;
    }
    __syncthreads();
    #pragma unroll
    for (int kk = 0; kk < 16; ++kk) {
      float a[8], b[8];
      *(float4*)(a)   = *(const float4*)&As[kk][ty*8];
      *(float4*)(a+4) = *(const float4*)&As[kk][ty*8+4];
      *(float4*)(b)   = *(const float4*)&Bs[kk][tx*8];
      *(float4*)(b+4) = *(const float4*)&Bs[kk][tx*8+4];
      #pragma unroll
      for (int i = 0; i < 8; ++i)
        #pragma unroll
        for (int j = 0; j < 8; ++j)
          acc[i][j] = fmaf(a[i], b[j], acc[i][j]);
    }
  }
  float bv[8];
  #pragma unroll
  for (int q = 0; q < 8; ++q) {
    int n = nbase + tx*8 + q;
    bv[q] = (bias1 ? bias1[n] : 0.f) + (bias2 ? bias2[n] : 0.f);
  }
  #pragma unroll
  for (int i = 0; i < 8; ++i) {
    size_t m = (size_t)(mbase + ty*8 + i);
    float4 o0 = make_float4(acc[i][0]+bv[0], acc[i][1]+bv[1], acc[i][2]+bv[2], acc[i][3]+bv[3]);
    float4 o1 = make_float4(acc[i][4]+bv[4], acc[i][5]+bv[5], acc[i][6]+bv[6], acc[i][7]+bv[7]);
    *(float4*)&C[m * N + nbase + tx*8]     = o0;
    *(float4*)&C[m * N + nbase + tx*8 + 4] = o1;
  }
}

// ---------------- the persistent decoder ----------------
__global__ __launch_bounds__(256) void decoder_kernel(
    const float* __restrict__ h0, const float* __restrict__ c0,
    const float* __restrict__ cmask,
    const float* __restrict__ W_hh,
    const float* __restrict__ W_inp, const float* __restrict__ b_inp_,
    const float* __restrict__ W_out, const float* __restrict__ b_out_,
    const float* __restrict__ vvec,
    float* __restrict__ ws, float* __restrict__ out) {
  // LDS: staged h (full 64x512, stride 528 => 2-way bank alias = free),
  //      block's weight rows, partial/alpha buffer. Total 161792 B (<160 KiB)
  //      => exactly 1 block/CU, all 256 blocks guaranteed co-resident.
  __shared__ float sh[64][528];
  __shared__ float sw[6144];   // [2][4][512] W_hh rows | [2][512] W_inp | [2][512] W_out2
  __shared__ float sph[512];   // phase A/B partials; phase D: alpha[0..127] + partial[128..383]

  int* flags = (int*)ws;
  float* hglob = ws + OFF_H;
  float* cstT  = ws + OFF_C;    // [512][64]
  float* hlp   = ws + OFF_HL;
  float* inpp  = ws + OFF_INP;
  float* hwp   = ws + OFF_HW;
  float* ep    = ws + OFF_E;
  float* maskp = ws + OFF_MASK;
  float* mlp   = ws + OFF_ML;
  int*   selp  = (int*)(ws + OFF_SEL);
  const float* x0wp = ws + OFF_X0W;
  const float* xwp  = ws + OFF_XW;
  const float* ctxp = ws + OFF_CTX;
  const float* cwop = ws + OFF_CWO;

  float* out_scores = out;
  float* out_ptrs   = out + (size_t)B*T*T;
  float* out_hf     = out_ptrs + (size_t)B*T;
  float* out_cf     = out_hf + (size_t)B*H;

  const int g = blockIdx.x, t = threadIdx.x;
  const int w = t >> 6, l = t & 63;
  int bar = 0;

  auto stage_full = [&](const float* src) {
    __syncthreads();
    #pragma unroll 8
    for (int r = 0; r < 32; ++r) {
      int q = r * 256 + t;               // float4 index over 64x512
      int bb = q >> 7, jj = q & 127;
      float4 v4 = *(const float4*)&src[(size_t)bb * 512 + jj * 4];
      *(float4*)&sh[bb][jj * 4] = v4;
    }
    __syncthreads();
  };

  // ---- init: copy states, mask, max_len ----
  {
    const int gid = g * NTHR + t;        // 0..65535
    if (gid < 32768) hglob[gid] = h0[gid];
    else {
      int z = gid - 32768, k = z >> 6, b = z & 63;
      cstT[k * 64 + b] = c0[(size_t)b * 512 + k];
    }
    if (gid < 8192)  maskp[gid] = cmask[gid];
    if (gid < 64) {
      float s_ = 0.f;
      for (int q = 0; q < 128; ++q) s_ += cmask[gid * 128 + q];
      mlp[gid] = s_;
    }
  }
  // ---- preload this block's weight rows into LDS ----
  {
    #pragma unroll
    for (int r = 0; r < 6; ++r) {
      int q = r * 256 + t;               // float4 index over 12 rows x 512
      int rq = q >> 7, cq = q & 127;
      const float* src;
      if (rq < 8)       src = W_hh  + ((size_t)(g*2 + (rq>>2)) + (size_t)(rq&3)*512) * 512;
      else if (rq < 10) src = W_inp + (size_t)(g*2 + (rq-8)) * 512;
      else              src = W_out + (size_t)(g*2 + (rq-10)) * 1024 + 512;
      float4 v4 = *(const float4*)&src[cq * 4];
      *(float4*)&sw[(size_t)q * 4] = v4;
    }
  }
  gridbar(flags, ++bar, g, t);

  // phase-C per-lane constants (v slice)
  float vreg[8];
  *(float4*)(vreg)   = *(const float4*)&vvec[l*8];
  *(float4*)(vreg+4) = *(const float4*)&vvec[l*8+4];

  for (int s = 0; s < T; ++s) {
    // ====== PHASE A: gates -> c_t, h_lstm (4-wave split: kk=w&1, j-half=w>>1) ======
    {
      stage_full(hglob);
      const int kk = g*2 + (w & 1);
      const int jh = (w >> 1) * 256;
      const float* hb = &sh[l][jh];
      const float* p0 = &sw[(w & 1) * 2048 + jh];
      const float* p1 = p0 + 512;
      const float* p2 = p0 + 1024;
      const float* p3 = p0 + 1536;
      float ai = 0.f, af = 0.f, ag = 0.f, ao = 0.f;
      #pragma unroll 4
      for (int j = 0; j < 256; j += 4) {
        float4 hv = *(const float4*)&hb[j];
        float4 w0 = *(const float4*)&p0[j];
        float4 w1 = *(const float4*)&p1[j];
        float4 w2 = *(const float4*)&p2[j];
        float4 w3 = *(const float4*)&p3[j];
        ai = fmaf(hv.x,w0.x, fmaf(hv.y,w0.y, fmaf(hv.z,w0.z, fmaf(hv.w,w0.w, ai))));
        af = fmaf(hv.x,w1.x, fmaf(hv.y,w1.y, fmaf(hv.z,w1.z, fmaf(hv.w,w1.w, af))));
        ag = fmaf(hv.x,w2.x, fmaf(hv.y,w2.y, fmaf(hv.z,w2.z, fmaf(hv.w,w2.w, ag))));
        ao = fmaf(hv.x,w3.x, fmaf(hv.y,w3.y, fmaf(hv.z,w3.z, fmaf(hv.w,w3.w, ao))));
      }
      if (w >= 2) *(float4*)&sph[((w & 1) * 64 + l) * 4] = make_float4(ai, af, ag, ao);
      __syncthreads();
      if (w < 2) {
        float4 pv = *(const float4*)&sph[(w * 64 + l) * 4];
        ai += pv.x; af += pv.y; ag += pv.z; ao += pv.w;
        const float* xrow = (s == 0) ? x0wp
                          : (xwp + ((size_t)l * 128 + (size_t)selp[l]) * 2048);
        float gi = ai + xrow[kk];
        float gf = af + xrow[kk + 512];
        float gg = ag + xrow[kk + 1024];
        float go = ao + xrow[kk + 1536];
        float cprev = cstT[kk * 64 + l];
        float ct = sigf(gf) * cprev + sigf(gi) * tanhf(gg);
        cstT[kk * 64 + l] = ct;
        hlp[(size_t)l * 512 + kk] = sigf(go) * tanhf(ct);
      }
    }
    gridbar(flags, ++bar, g, t);

    // ====== PHASE B: inp = hl@W_inp^T + b_inp ; hWo2 = hl@Wout2^T + b_out ======
    {
      stage_full(hlp);
      const int ii_ = g*2 + (w & 1);
      const int jh = (w >> 1) * 256;
      const float* hb  = &sh[l][jh];
      const float* pi_ = &sw[4096 + (w & 1) * 512 + jh];
      const float* po_ = &sw[5120 + (w & 1) * 512 + jh];
      float a1 = 0.f, a2 = 0.f;
      #pragma unroll 4
      for (int j = 0; j < 256; j += 4) {
        float4 hv = *(const float4*)&hb[j];
        float4 w0 = *(const float4*)&pi_[j];
        float4 w1 = *(const float4*)&po_[j];
        a1 = fmaf(hv.x,w0.x, fmaf(hv.y,w0.y, fmaf(hv.z,w0.z, fmaf(hv.w,w0.w, a1))));
        a2 = fmaf(hv.x,w1.x, fmaf(hv.y,w1.y, fmaf(hv.z,w1.z, fmaf(hv.w,w1.w, a2))));
      }
      if (w >= 2) *(float2*)&sph[((w & 1) * 64 + l) * 2] = make_float2(a1, a2);
      __syncthreads();
      if (w < 2) {
        float2 pv = *(const float2*)&sph[(w * 64 + l) * 2];
        a1 += pv.x; a2 += pv.y;
        size_t idx = (size_t)l * 512 + ii_;
        inpp[idx] = a1 + b_inp_[ii_];
        hwp[idx]  = a2 + b_out_[ii_];
      }
    }
    gridbar(flags, ++bar, g, t);

    // ====== PHASE C: e[b,t] = v . tanh(ctx_lin + inp), write masked scores ======
    {
      const int b_ = g >> 2;
      const int tbase = (g & 3) * 32 + w * 8;
      float ii[8];
      *(float4*)(ii)   = *(const float4*)&inpp[(size_t)b_ * 512 + l*8];
      *(float4*)(ii+4) = *(const float4*)&inpp[(size_t)b_ * 512 + l*8 + 4];
      #pragma unroll
      for (int q = 0; q < 8; ++q) {
        int tc = tbase + q;
        const float* cr = ctxp + ((size_t)(b_ * 128 + tc)) * 512 + l * 8;
        float4 c0_ = *(const float4*)cr;
        float4 c1_ = *(const float4*)(cr + 4);
        float acc = vreg[0]*tanhf(c0_.x + ii[0]) + vreg[1]*tanhf(c0_.y + ii[1])
                  + vreg[2]*tanhf(c0_.z + ii[2]) + vreg[3]*tanhf(c0_.w + ii[3])
                  + vreg[4]*tanhf(c1_.x + ii[4]) + vreg[5]*tanhf(c1_.y + ii[5])
                  + vreg[6]*tanhf(c1_.z + ii[6]) + vreg[7]*tanhf(c1_.w + ii[7]);
        #pragma unroll
        for (int off = 32; off; off >>= 1) acc += __shfl_xor(acc, off, 64);
        if (l == 0) {
          float mk = maskp[b_ * 128 + tc];
          float sc = (mk > 0.f) ? acc : NEGV;
          ep[b_ * 128 + tc] = sc;
          out_scores[((size_t)b_ * 128 + s) * 128 + tc] = sc;
        }
      }
    }
    gridbar(flags, ++bar, g, t);

    // ====== PHASE D: softmax, selection, h_t ======
    {
      const int b_ = g >> 2, is = (g & 3) << 7;
      if (w == 0) {
        float s0 = ep[b_ * 128 + l], s1 = ep[b_ * 128 + 64 + l];
        float mx = fmaxf(s0, s1);
        #pragma unroll
        for (int off = 32; off; off >>= 1) mx = fmaxf(mx, __shfl_xor(mx, off, 64));
        float x0 = expf(s0 - mx), x1 = expf(s1 - mx);
        float sum = x0 + x1;
        #pragma unroll
        for (int off = 32; off; off >>= 1) sum += __shfl_xor(sum, off, 64);
        float a0 = x0 / sum, a1 = x1 / sum;
        sph[l] = a0; sph[64 + l] = a1;
        if ((g & 3) == 0) {
          float m0 = maskp[b_ * 128 + l], m1 = maskp[b_ * 128 + 64 + l];
          float p0 = a0 * m0, p1 = a1 * m1;
          float pv; int pi;
          if (p1 > p0) { pv = p1; pi = l + 64; } else { pv = p0; pi = l; }
          #pragma unroll
          for (int off = 32; off; off >>= 1) {
            float ov = __shfl_xor(pv, off, 64);
            int   oi = __shfl_xor(pi, off, 64);
            if (ov > pv || (ov == pv && oi < pi)) { pv = ov; pi = oi; }
          }
          if (l == 0) {
            int se = (mlp[b_] > (float)s) ? pi : s;
            selp[b_] = se;
            maskp[b_ * 128 + se] = 0.f;
            out_ptrs[b_ * 128 + s] = (float)se;
          }
        }
      }
      __syncthreads();
      {
        const int io = t & 127, half = t >> 7;
        const int i = is + io;
        const float* aw = &sph[half * 64];
        const float* cw = cwop + ((size_t)(b_ * 128 + half * 64)) * 512 + i;
        float acc0 = 0.f, acc1 = 0.f, acc2 = 0.f, acc3 = 0.f;
        #pragma unroll 8
        for (int tc = 0; tc < 64; tc += 4) {
          acc0 = fmaf(aw[tc+0], cw[(size_t)(tc+0) * 512], acc0);
          acc1 = fmaf(aw[tc+1], cw[(size_t)(tc+1) * 512], acc1);
          acc2 = fmaf(aw[tc+2], cw[(size_t)(tc+2) * 512], acc2);
          acc3 = fmaf(aw[tc+3], cw[(size_t)(tc+3) * 512], acc3);
        }
        sph[128 + t] = (acc0 + acc1) + (acc2 + acc3);
      }
      __syncthreads();
      if (t < 128) {
        const int i = is + t;
        float tot = hwp[(size_t)b_ * 512 + i] + sph[128 + t] + sph[256 + t];
        hglob[(size_t)b_ * 512 + i] = tanhf(tot);
      }
    }
    gridbar(flags, ++bar, g, t);
  }

  // ---- epilogue: h_f, c_f ----
  {
    const int gid = g * NTHR + t;
    if (gid < 32768) out_hf[gid] = hglob[gid];
    else {
      int z = gid - 32768, b = z >> 9, k = z & 511;
      out_cf[z] = cstT[k * 64 + b];
    }
  }
}

extern "C" void kernel_launch(void* const* d_in, const int* in_sizes, int n_in,
                              void* d_out, int out_size, void* d_ws, size_t ws_size,
                              hipStream_t stream) {
  (void)in_sizes; (void)n_in; (void)out_size; (void)ws_size;
  const float* inputs    = (const float*)d_in[0];
  const float* h0        = (const float*)d_in[1];
  const float* c0        = (const float*)d_in[2];
  const float* candidate = (const float*)d_in[3];
  const float* cmask     = (const float*)d_in[4];
  const float* input0    = (const float*)d_in[5];
  const float* W_ih      = (const float*)d_in[6];
  const float* b_ih      = (const float*)d_in[7];
  const float* W_hh      = (const float*)d_in[8];
  const float* b_hh      = (const float*)d_in[9];
  const float* W_out     = (const float*)d_in[10];
  const float* b_out     = (const float*)d_in[11];
  const float* W_inp     = (const float*)d_in[12];
  const float* b_inp     = (const float*)d_in[13];
  const float* W_ctx     = (const float*)d_in[14];
  const float* b_ctx     = (const float*)d_in[15];
  const float* v         = (const float*)d_in[16];
  float* ws  = (float*)d_ws;
  float* outp = (float*)d_out;

  // zero the barrier flag array (256 ints)
  (void)hipMemsetAsync(d_ws, 0, 1024, stream);

  // x0 row: input0 @ W_ih^T + b_ih + b_hh
  x0w_kernel<<<512, 256, 0, stream>>>(input0, W_ih, b_ih, b_hh, ws + OFF_X0W);

  // xW table: inputs(8192,512) @ W_ih(2048,512)^T + b_ih + b_hh
  gemm_abt<<<dim3(16, 64), 256, 0, stream>>>(inputs, W_ih, b_ih, b_hh,
                                             ws + OFF_XW, 8192, 2048, 512, 512);
  // ctx_lin: candidate(8192,512) @ W_ctx(512,512)^T + b_ctx
  gemm_abt<<<dim3(4, 64), 256, 0, stream>>>(candidate, W_ctx, b_ctx, nullptr,
                                            ws + OFF_CTX, 8192, 512, 512, 512);
  // ctxWo: ctx_lin @ W_out[:, :512]^T   (W_out row stride 1024)
  gemm_abt<<<dim3(4, 64), 256, 0, stream>>>(ws + OFF_CTX, W_out, nullptr, nullptr,
                                            ws + OFF_CWO, 8192, 512, 512, 1024);

  decoder_kernel<<<NB, NTHR, 0, stream>>>(h0, c0, cmask, W_hh, W_inp, b_inp,
                                          W_out, b_out, v, ws, outp);
}

// Round 4
// 9696.931 us; speedup vs baseline: 2.4329x; 1.3752x over previous
//
#include <hip/hip_runtime.h>
#include <cstddef>
#include <cstdint>

// Pointer-network decoder, B=64, T=128, D=512, H=512.
// Round 4: 4 INDEPENDENT groups of 64 blocks (16 batches each) — batches are
// independent, so barriers are 64-wide per group, not 256-wide. Weights live
// in LDS (conflict-free chunk-padded layout); h/h_lstm read directly from
// global, coalesced, no LDS staging.

#define NEGV (-1e9f)

static constexpr int T = 128;
static constexpr int NB = 256, NTHR = 256;
static constexpr int NG = 4, GBLK = 64, BG = 16;   // groups, blocks/group, batches/group

// ---- workspace layout (element offsets, fp32) ----
static constexpr size_t OFF_SYNC = 0;                         // 512 ints: flags[4][64] + epoch[4][32]
static constexpr size_t OFF_H    = 512;                       // [64][512] h (row-major)
static constexpr size_t OFF_C    = OFF_H    + 64*512;         // [64][512] c
static constexpr size_t OFF_HL   = OFF_C    + 64*512;         // [64][512] h_lstm
static constexpr size_t OFF_INP  = OFF_HL   + 64*512;         // [64][512] inp (incl b_inp)
static constexpr size_t OFF_HW   = OFF_INP  + 64*512;         // [64][512] h@Wout2^T + b_out
static constexpr size_t OFF_E    = OFF_HW   + 64*512;         // [64][128] masked scores
static constexpr size_t OFF_MASK = OFF_E    + 64*128;         // [64][128]
static constexpr size_t OFF_ML   = OFF_MASK + 64*128;         // [64] max_len
static constexpr size_t OFF_SEL  = OFF_ML   + 64;             // [64] (int)
static constexpr size_t OFF_X0W  = OFF_SEL  + 64;             // [2048]
static constexpr size_t OFF_XW   = OFF_X0W  + 2048;           // [8192][2048]
static constexpr size_t OFF_CTX  = OFF_XW   + (size_t)8192*2048; // [8192][512]
static constexpr size_t OFF_CWO  = OFF_CTX  + (size_t)8192*512;  // [8192][512]

__device__ __forceinline__ float sigf(float x) { return 1.0f / (1.0f + expf(-x)); }

// ---------------- group barrier: 64 flags + aggregator + epoch broadcast ----------------
__device__ __forceinline__ void gridbar(int* gflags, int* gepoch, int target, int gl, int t) {
  __syncthreads();
  if (t == 0) {
    __hip_atomic_store(&gflags[gl], target, __ATOMIC_RELEASE, __HIP_MEMORY_SCOPE_AGENT);
  }
  if (gl == 0) {
    if (t < 64) {               // aggregator wave: one flag per lane
      int miss = 0;
      for (;;) {
        int f = __hip_atomic_load(&gflags[t], __ATOMIC_RELAXED, __HIP_MEMORY_SCOPE_AGENT);
        if (__all(f >= target)) break;
        __builtin_amdgcn_s_sleep(1);
        if (++miss > 50000000) break;
      }
      if (t == 0)
        __hip_atomic_store(gepoch, target, __ATOMIC_RELEASE, __HIP_MEMORY_SCOPE_AGENT);
    }
  } else {
    if (t == 0) {
      int miss = 0;
      while (__hip_atomic_load(gepoch, __ATOMIC_RELAXED, __HIP_MEMORY_SCOPE_AGENT) < target) {
        __builtin_amdgcn_s_sleep(2);
        if (++miss > 50000000) break;
      }
    }
  }
  __syncthreads();
  __builtin_amdgcn_fence(__ATOMIC_ACQUIRE, "agent");
}

// ---------------- precompute: x0 row ----------------
__global__ __launch_bounds__(256) void x0w_kernel(
    const float* __restrict__ input0, const float* __restrict__ W_ih,
    const float* __restrict__ b_ih, const float* __restrict__ b_hh,
    float* __restrict__ x0w) {
  int wid = (blockIdx.x * 256 + threadIdx.x) >> 6;
  int l = threadIdx.x & 63;
  const float* wr = W_ih + (size_t)wid * 512;
  float acc = 0.f;
  #pragma unroll
  for (int q = 0; q < 8; ++q) acc += input0[l*8+q] * wr[l*8+q];
  #pragma unroll
  for (int off = 32; off; off >>= 1) acc += __shfl_xor(acc, off, 64);
  if (l == 0) x0w[wid] = acc + b_ih[wid] + b_hh[wid];
}

// ---------------- precompute: tiled fp32 GEMM, C = A@B^T + bias1 + bias2 ----------------
__global__ __launch_bounds__(256) void gemm_abt(
    const float* __restrict__ A, const float* __restrict__ Bm,
    const float* __restrict__ bias1, const float* __restrict__ bias2,
    float* __restrict__ C, int M, int N, int K, int ldb) {
  __shared__ float As[16][132];
  __shared__ float Bs[16][132];
  const int t = threadIdx.x;
  const int tx = t & 15, ty = t >> 4;
  const int mbase = blockIdx.y * 128, nbase = blockIdx.x * 128;
  float acc[8][8] = {};
  for (int kc = 0; kc < K; kc += 16) {
    __syncthreads();
    #pragma unroll
    for (int r = 0; r < 2; ++r) {
      int q = r * 256 + t;
      int row = q >> 2, kq = (q & 3) * 4;
      float4 va = *(const float4*)&A[(size_t)(mbase + row) * K + kc + kq];
      As[kq+0][row] = va.x; As[kq+1][row] = va.y; As[kq+2][row] = va.z; As[kq+3][row] = va.w;
      float4 vb = *(const float4*)&Bm[(size_t)(nbase + row) * ldb + kc + kq];
      Bs[kq+0][row] = vb.x; Bs[kq+1][row] = vb.y; Bs[kq+2][row] = vb.z; Bs[kq+3][row] = vb.w;
    }
    __syncthreads();
    #pragma unroll
    for (int kk = 0; kk < 16; ++kk) {
      float a[8], b[8];
      *(float4*)(a)   = *(const float4*)&As[kk][ty*8];
      *(float4*)(a+4) = *(const float4*)&As[kk][ty*8+4];
      *(float4*)(b)   = *(const float4*)&Bs[kk][tx*8];
      *(float4*)(b+4) = *(const float4*)&Bs[kk][tx*8+4];
      #pragma unroll
      for (int i = 0; i < 8; ++i)
        #pragma unroll
        for (int j = 0; j < 8; ++j)
          acc[i][j] = fmaf(a[i], b[j], acc[i][j]);
    }
  }
  float bv[8];
  #pragma unroll
  for (int q = 0; q < 8; ++q) {
    int n = nbase + tx*8 + q;
    bv[q] = (bias1 ? bias1[n] : 0.f) + (bias2 ? bias2[n] : 0.f);
  }
  #pragma unroll
  for (int i = 0; i < 8; ++i) {
    size_t m = (size_t)(mbase + ty*8 + i);
    float4 o0 = make_float4(acc[i][0]+bv[0], acc[i][1]+bv[1], acc[i][2]+bv[2], acc[i][3]+bv[3]);
    float4 o1 = make_float4(acc[i][4]+bv[4], acc[i][5]+bv[5], acc[i][6]+bv[6], acc[i][7]+bv[7]);
    *(float4*)&C[m * N + nbase + tx*8]     = o0;
    *(float4*)&C[m * N + nbase + tx*8 + 4] = o1;
  }
}

// ---------------- the persistent decoder ----------------
// LDS weight layout: row length 576 floats; chunk c (of 16, 32 floats each) at
// row*576 + c*36. 36*4B = 144B = 9*16B -> b128-aligned; bank base 4*c -> at most
// 2-way aliasing across the 16 js-lanes (free).
__global__ __launch_bounds__(256) void decoder_kernel(
    const float* __restrict__ h0, const float* __restrict__ c0,
    const float* __restrict__ cmask,
    const float* __restrict__ W_hh,
    const float* __restrict__ W_inp, const float* __restrict__ b_inp_,
    const float* __restrict__ W_out, const float* __restrict__ b_out_,
    const float* __restrict__ vvec,
    float* __restrict__ ws, float* __restrict__ out) {
  __shared__ float swA[32*576];   // [gate*8+rl][chunked 512]  W_hh rows     (73.7 KB)
  __shared__ float swB[16*576];   // [0..7]=W_inp rows, [8..15]=W_out2 rows  (36.9 KB)
  __shared__ float sph[512];      // A/B handoff, D alpha+partials
  __shared__ float sbias[16];

  int* syncp = (int*)ws;
  float* hrow  = ws + OFF_H;
  float* crow  = ws + OFF_C;
  float* hlrow = ws + OFF_HL;
  float* inpp  = ws + OFF_INP;
  float* hwp   = ws + OFF_HW;
  float* ep    = ws + OFF_E;
  float* maskp = ws + OFF_MASK;
  float* mlp   = ws + OFF_ML;
  int*   selp  = (int*)(ws + OFF_SEL);
  const float* x0wp = ws + OFF_X0W;
  const float* xwp  = ws + OFF_XW;
  const float* ctxp = ws + OFF_CTX;
  const float* cwop = ws + OFF_CWO;

  float* out_scores = out;
  float* out_ptrs   = out + (size_t)64*128*128;
  float* out_hf     = out_ptrs + 64*128;
  float* out_cf     = out_hf + 64*512;

  const int g = blockIdx.x, t = threadIdx.x;
  const int gg = g >> 6, gl = g & 63;       // group, block-in-group
  const int w = t >> 6, l = t & 63;
  const int bl = t >> 4, js = t & 15;       // phase A/B mapping: (batch-local, j-slice)
  int* gflags = syncp + gg * 64;
  int* gepoch = syncp + 256 + gg * 32;
  int bar = 0;

  // ---- stage this block's weight rows into LDS (chunk-padded) ----
  {
    const int a = t >> 3, seg = t & 7;      // swA: 32 rows, 8 segs of 64 floats
    const int gate = a >> 3, rl = a & 7;
    const float* srcrow = W_hh + ((size_t)(gate*512 + gl*8 + rl)) * 512;
    #pragma unroll
    for (int c2 = 0; c2 < 2; ++c2) {
      const int ch = seg*2 + c2;
      const float4* s4 = (const float4*)&srcrow[ch*32];
      float4* d4 = (float4*)&swA[a*576 + ch*36];
      #pragma unroll
      for (int u = 0; u < 8; ++u) d4[u] = s4[u];
    }
    const int a2 = t >> 4, seg2 = t & 15;   // swB: 16 rows, 16 segs of 32 floats
    const float* srcrow2 = (a2 < 8) ? (W_inp + (size_t)(gl*8 + a2) * 512)
                                    : (W_out + (size_t)(gl*8 + a2 - 8) * 1024 + 512);
    const float4* s42 = (const float4*)&srcrow2[seg2*32];
    float4* d42 = (float4*)&swB[a2*576 + seg2*36];
    #pragma unroll
    for (int u = 0; u < 8; ++u) d42[u] = s42[u];
    if (t < 16) sbias[t] = (t < 8) ? b_inp_[gl*8 + t] : b_out_[gl*8 + t - 8];
  }

  // ---- group-local init: h, c, mask, max_len ----
  {
    const int idx = gl * NTHR + t;          // 0..16383 within group
    const int base = gg * 8192;             // 16 batches * 512
    if (idx < 8192) hrow[base + idx] = h0[base + idx];
    else            crow[base + idx - 8192] = c0[base + idx - 8192];
    if (idx < 2048) maskp[gg*2048 + idx] = cmask[gg*2048 + idx];
    if (gl == 0 && t < BG) {
      float s_ = 0.f;
      for (int q = 0; q < 128; ++q) s_ += cmask[(gg*BG + t)*128 + q];
      mlp[gg*BG + t] = s_;
    }
  }
  gridbar(gflags, gepoch, ++bar, gl, t);

  // phase-C per-lane constants
  float vreg[8];
  *(float4*)(vreg)   = *(const float4*)&vvec[l*8];
  *(float4*)(vreg+4) = *(const float4*)&vvec[l*8+4];

  for (int s = 0; s < T; ++s) {
    // ====== PHASE A: gates -> c_t, h_lstm ======
    // thread (bl, js): batch gg*16+bl, j-slice [js*32, js*32+32); 32 gate-rows.
    {
      const int b = gg*BG + bl;
      const float* hb = hrow + (size_t)b*512 + js*32;
      float hbuf[32];
      #pragma unroll
      for (int q = 0; q < 8; ++q) *(float4*)&hbuf[q*4] = *(const float4*)&hb[q*4];
      float acc[32];
      #pragma unroll
      for (int a = 0; a < 32; ++a) acc[a] = 0.f;
      const float* wbase = &swA[js*36];
      #pragma unroll
      for (int a = 0; a < 32; ++a) {
        const float* wr = wbase + a*576;
        #pragma unroll
        for (int j = 0; j < 32; j += 4) {
          float4 wv = *(const float4*)&wr[j];
          acc[a] = fmaf(hbuf[j+0], wv.x, fmaf(hbuf[j+1], wv.y,
                   fmaf(hbuf[j+2], wv.z, fmaf(hbuf[j+3], wv.w, acc[a]))));
        }
      }
      #pragma unroll
      for (int a = 0; a < 32; ++a) {
        acc[a] += __shfl_xor(acc[a], 1, 64);
        acc[a] += __shfl_xor(acc[a], 2, 64);
        acc[a] += __shfl_xor(acc[a], 4, 64);
        acc[a] += __shfl_xor(acc[a], 8, 64);
      }
      if (js == 0) {
        #pragma unroll
        for (int a = 0; a < 32; ++a) sph[bl*32 + a] = acc[a];
      }
      __syncthreads();
      if (js < 8) {
        const int r = gl*8 + js;
        float pi = sph[bl*32 + 0*8 + js];
        float pf = sph[bl*32 + 1*8 + js];
        float pg = sph[bl*32 + 2*8 + js];
        float po = sph[bl*32 + 3*8 + js];
        const float* xrow = (s == 0) ? x0wp
                          : (xwp + ((size_t)b*128 + (size_t)selp[b]) * 2048);
        float gi  = pi + xrow[0*512 + r];
        float gf  = pf + xrow[1*512 + r];
        float gg2 = pg + xrow[2*512 + r];
        float go  = po + xrow[3*512 + r];
        float cp = crow[(size_t)b*512 + r];
        float ct = sigf(gf)*cp + sigf(gi)*tanhf(gg2);
        crow[(size_t)b*512 + r] = ct;
        hlrow[(size_t)b*512 + r] = sigf(go)*tanhf(ct);
      }
    }
    gridbar(gflags, gepoch, ++bar, gl, t);

    // ====== PHASE B: inp = hl@W_inp^T + b_inp ; hw = hl@Wout2^T + b_out ======
    {
      const int b = gg*BG + bl;
      const float* hb = hlrow + (size_t)b*512 + js*32;
      float hbuf[32];
      #pragma unroll
      for (int q = 0; q < 8; ++q) *(float4*)&hbuf[q*4] = *(const float4*)&hb[q*4];
      float acc[16];
      #pragma unroll
      for (int a = 0; a < 16; ++a) acc[a] = 0.f;
      const float* wbase = &swB[js*36];
      #pragma unroll
      for (int a = 0; a < 16; ++a) {
        const float* wr = wbase + a*576;
        #pragma unroll
        for (int j = 0; j < 32; j += 4) {
          float4 wv = *(const float4*)&wr[j];
          acc[a] = fmaf(hbuf[j+0], wv.x, fmaf(hbuf[j+1], wv.y,
                   fmaf(hbuf[j+2], wv.z, fmaf(hbuf[j+3], wv.w, acc[a]))));
        }
      }
      #pragma unroll
      for (int a = 0; a < 16; ++a) {
        acc[a] += __shfl_xor(acc[a], 1, 64);
        acc[a] += __shfl_xor(acc[a], 2, 64);
        acc[a] += __shfl_xor(acc[a], 4, 64);
        acc[a] += __shfl_xor(acc[a], 8, 64);
      }
      if (js == 0) {
        #pragma unroll
        for (int a = 0; a < 16; ++a) sph[bl*16 + a] = acc[a];
      }
      __syncthreads();
      if (js < 8) {
        const int r = gl*8 + js;
        inpp[(size_t)b*512 + r] = sph[bl*16 + js]     + sbias[js];
        hwp [(size_t)b*512 + r] = sph[bl*16 + 8 + js] + sbias[8 + js];
      }
    }
    gridbar(gflags, gepoch, ++bar, gl, t);

    // ====== PHASE C: e[b,t] = v . tanh(ctx_lin + inp), masked scores ======
    {
      const int b_ = gg*BG + (gl >> 2);
      const int tbase = (gl & 3)*32 + w*8;
      float ii[8];
      *(float4*)(ii)   = *(const float4*)&inpp[(size_t)b_*512 + l*8];
      *(float4*)(ii+4) = *(const float4*)&inpp[(size_t)b_*512 + l*8 + 4];
      #pragma unroll
      for (int q = 0; q < 8; ++q) {
        int tc = tbase + q;
        const float* cr = ctxp + ((size_t)(b_*128 + tc))*512 + l*8;
        float4 c0_ = *(const float4*)cr;
        float4 c1_ = *(const float4*)(cr + 4);
        float acc = vreg[0]*tanhf(c0_.x + ii[0]) + vreg[1]*tanhf(c0_.y + ii[1])
                  + vreg[2]*tanhf(c0_.z + ii[2]) + vreg[3]*tanhf(c0_.w + ii[3])
                  + vreg[4]*tanhf(c1_.x + ii[4]) + vreg[5]*tanhf(c1_.y + ii[5])
                  + vreg[6]*tanhf(c1_.z + ii[6]) + vreg[7]*tanhf(c1_.w + ii[7]);
        #pragma unroll
        for (int off = 32; off; off >>= 1) acc += __shfl_xor(acc, off, 64);
        if (l == 0) {
          float mk = maskp[b_*128 + tc];
          float sc = (mk > 0.f) ? acc : NEGV;
          ep[b_*128 + tc] = sc;
          out_scores[((size_t)b_*128 + s)*128 + tc] = sc;
        }
      }
    }
    gridbar(gflags, gepoch, ++bar, gl, t);

    // ====== PHASE D: softmax, selection, h_t ======
    {
      const int b_ = gg*BG + (gl >> 2), is = (gl & 3) << 7;
      if (w == 0) {
        float s0 = ep[b_*128 + l], s1 = ep[b_*128 + 64 + l];
        float mx = fmaxf(s0, s1);
        #pragma unroll
        for (int off = 32; off; off >>= 1) mx = fmaxf(mx, __shfl_xor(mx, off, 64));
        float x0 = expf(s0 - mx), x1 = expf(s1 - mx);
        float sum = x0 + x1;
        #pragma unroll
        for (int off = 32; off; off >>= 1) sum += __shfl_xor(sum, off, 64);
        float a0 = x0 / sum, a1 = x1 / sum;
        sph[l] = a0; sph[64 + l] = a1;
        if ((gl & 3) == 0) {
          float m0 = maskp[b_*128 + l], m1 = maskp[b_*128 + 64 + l];
          float p0 = a0 * m0, p1 = a1 * m1;
          float pv; int pi;
          if (p1 > p0) { pv = p1; pi = l + 64; } else { pv = p0; pi = l; }
          #pragma unroll
          for (int off = 32; off; off >>= 1) {
            float ov = __shfl_xor(pv, off, 64);
            int   oi = __shfl_xor(pi, off, 64);
            if (ov > pv || (ov == pv && oi < pi)) { pv = ov; pi = oi; }
          }
          if (l == 0) {
            int se = (mlp[b_] > (float)s) ? pi : s;
            selp[b_] = se;
            maskp[b_*128 + se] = 0.f;
            out_ptrs[b_*128 + s] = (float)se;
          }
        }
      }
      __syncthreads();
      {
        const int io = t & 127, half = t >> 7;
        const int i = is + io;
        const float* aw = &sph[half * 64];
        const float* cw = cwop + ((size_t)(b_*128 + half*64))*512 + i;
        float acc0 = 0.f, acc1 = 0.f, acc2 = 0.f, acc3 = 0.f;
        #pragma unroll 8
        for (int tc = 0; tc < 64; tc += 4) {
          acc0 = fmaf(aw[tc+0], cw[(size_t)(tc+0)*512], acc0);
          acc1 = fmaf(aw[tc+1], cw[(size_t)(tc+1)*512], acc1);
          acc2 = fmaf(aw[tc+2], cw[(size_t)(tc+2)*512], acc2);
          acc3 = fmaf(aw[tc+3], cw[(size_t)(tc+3)*512], acc3);
        }
        sph[128 + t] = (acc0 + acc1) + (acc2 + acc3);
      }
      __syncthreads();
      if (t < 128) {
        const int i = is + t;
        float tot = hwp[(size_t)b_*512 + i] + sph[128 + t] + sph[256 + t];
        hrow[(size_t)b_*512 + i] = tanhf(tot);
      }
    }
    gridbar(gflags, gepoch, ++bar, gl, t);
  }

  // ---- group-local epilogue: h_f, c_f ----
  {
    const int idx = gl * NTHR + t;          // 0..16383
    const int base = gg * 8192;
    if (idx < 8192) out_hf[base + idx] = hrow[base + idx];
    else            out_cf[base + idx - 8192] = crow[base + idx - 8192];
  }
}

extern "C" void kernel_launch(void* const* d_in, const int* in_sizes, int n_in,
                              void* d_out, int out_size, void* d_ws, size_t ws_size,
                              hipStream_t stream) {
  (void)in_sizes; (void)n_in; (void)out_size; (void)ws_size;
  const float* inputs    = (const float*)d_in[0];
  const float* h0        = (const float*)d_in[1];
  const float* c0        = (const float*)d_in[2];
  const float* candidate = (const float*)d_in[3];
  const float* cmask     = (const float*)d_in[4];
  const float* input0    = (const float*)d_in[5];
  const float* W_ih      = (const float*)d_in[6];
  const float* b_ih      = (const float*)d_in[7];
  const float* W_hh      = (const float*)d_in[8];
  const float* b_hh      = (const float*)d_in[9];
  const float* W_out     = (const float*)d_in[10];
  const float* b_out     = (const float*)d_in[11];
  const float* W_inp     = (const float*)d_in[12];
  const float* b_inp     = (const float*)d_in[13];
  const float* W_ctx     = (const float*)d_in[14];
  const float* b_ctx     = (const float*)d_in[15];
  const float* v         = (const float*)d_in[16];
  float* ws  = (float*)d_ws;
  float* outp = (float*)d_out;

  // zero barrier flags + epochs (512 ints)
  (void)hipMemsetAsync(d_ws, 0, 2048, stream);

  // x0 row: input0 @ W_ih^T + b_ih + b_hh
  x0w_kernel<<<512, 256, 0, stream>>>(input0, W_ih, b_ih, b_hh, ws + OFF_X0W);

  // xW table: inputs(8192,512) @ W_ih(2048,512)^T + b_ih + b_hh
  gemm_abt<<<dim3(16, 64), 256, 0, stream>>>(inputs, W_ih, b_ih, b_hh,
                                             ws + OFF_XW, 8192, 2048, 512, 512);
  // ctx_lin: candidate(8192,512) @ W_ctx(512,512)^T + b_ctx
  gemm_abt<<<dim3(4, 64), 256, 0, stream>>>(candidate, W_ctx, b_ctx, nullptr,
                                            ws + OFF_CTX, 8192, 512, 512, 512);
  // ctxWo: ctx_lin @ W_out[:, :512]^T   (W_out row stride 1024)
  gemm_abt<<<dim3(4, 64), 256, 0, stream>>>(ws + OFF_CTX, W_out, nullptr, nullptr,
                                            ws + OFF_CWO, 8192, 512, 512, 1024);

  decoder_kernel<<<NB, NTHR, 0, stream>>>(h0, c0, cmask, W_hh, W_inp, b_inp,
                                          W_out, b_out, v, ws, outp);
}